// Round 9
// baseline (143.096 us; speedup 1.0000x reference)
//
#include <hip/hip_runtime.h>
#include <hip/hip_fp16.h>

#define DIM 1024
#define NB 8
#define CBLK 8
#define LSTRIDE 9  // half2 per row: 8 + 1 pad (odd stride -> conflict-free strided reads)

typedef float vfloat4 __attribute__((ext_vector_type(4)));

// LDS tile: 1024 rows x (8+1) half2 = 36864 B -> up to 4 blocks/CU.
__device__ __forceinline__ int lidx(int r, int c) {
  return r * LSTRIDE + c;
}

__device__ __forceinline__ unsigned rflu(unsigned x) {
  return (unsigned)__builtin_amdgcn_readfirstlane((int)x);
}
__device__ __forceinline__ unsigned h2u(__half2 h) {
  union { __half2 h; unsigned u; } c; c.h = h; return c.u;
}
__device__ __forceinline__ __half2 u2h(unsigned u) {
  union { unsigned u; __half2 h; } c; c.u = u; return c.h;
}
// swap halves: (a,b) -> (b,a)
__device__ __forceinline__ __half2 h2swap(__half2 x) {
  unsigned u = h2u(x);
  return u2h((u >> 16) | (u << 16));
}
__device__ __forceinline__ __half2 h2dup(float f) {
  return __half2half2(__float2half(f));
}

struct __align__(16) H2x4 { __half2 h[4]; };

// Packed complex 4x4 matvec, in place along `stride` (array form, R6-proven).
__device__ __forceinline__ void mv4p(__half2* v, const int stride,
                                     const unsigned (&Wre2)[4][4],
                                     const unsigned (&Wimn)[4][4]) {
  __half2 x0 = v[0], x1 = v[stride], x2 = v[2 * stride], x3 = v[3 * stride];
  __half2 s0 = h2swap(x0), s1 = h2swap(x1), s2 = h2swap(x2), s3 = h2swap(x3);
  #pragma unroll
  for (int p = 0; p < 4; ++p) {
    __half2 a = u2h(Wre2[p][0]) * x0;
    a = __hfma2(u2h(Wimn[p][0]), s0, a);
    a = __hfma2(u2h(Wre2[p][2]), x2, a);
    a = __hfma2(u2h(Wimn[p][2]), s2, a);
    __half2 b = u2h(Wre2[p][1]) * x1;
    b = __hfma2(u2h(Wimn[p][1]), s1, b);
    b = __hfma2(u2h(Wre2[p][3]), x3, b);
    b = __hfma2(u2h(Wimn[p][3]), s3, b);
    v[p * stride] = a + b;
  }
}

// Scalar-argument complex 4x4 matvec (spill-proof: no arrays).
__device__ __forceinline__ void cmv4(__half2 x0, __half2 x1, __half2 x2, __half2 x3,
                                     __half2& y0, __half2& y1, __half2& y2, __half2& y3,
                                     const unsigned (&Wre2)[4][4],
                                     const unsigned (&Wimn)[4][4]) {
  __half2 s0 = h2swap(x0), s1 = h2swap(x1), s2 = h2swap(x2), s3 = h2swap(x3);
#define QROW(p, Y)                                                       \
  {                                                                      \
    __half2 a = u2h(Wre2[p][0]) * x0;                                    \
    a = __hfma2(u2h(Wimn[p][0]), s0, a);                                 \
    a = __hfma2(u2h(Wre2[p][2]), x2, a);                                 \
    a = __hfma2(u2h(Wimn[p][2]), s2, a);                                 \
    __half2 b = u2h(Wre2[p][1]) * x1;                                    \
    b = __hfma2(u2h(Wimn[p][1]), s1, b);                                 \
    b = __hfma2(u2h(Wre2[p][3]), x3, b);                                 \
    b = __hfma2(u2h(Wimn[p][3]), s3, b);                                 \
    Y = a + b;                                                           \
  }
  QROW(0, y0) QROW(1, y1) QROW(2, y2) QROW(3, y3)
#undef QROW
}

// Scalar-argument real-input variant: x = (re,re), Wri = (Wre,Wim).
__device__ __forceinline__ void cmv4r(__half2 x0, __half2 x1, __half2 x2, __half2 x3,
                                      __half2& y0, __half2& y1, __half2& y2, __half2& y3,
                                      const unsigned (&Wri)[4][4]) {
#define QROWR(p, Y)                                                      \
  {                                                                      \
    __half2 a = u2h(Wri[p][0]) * x0;                                     \
    a = __hfma2(u2h(Wri[p][2]), x2, a);                                  \
    __half2 b = u2h(Wri[p][1]) * x1;                                     \
    b = __hfma2(u2h(Wri[p][3]), x3, b);                                  \
    Y = a + b;                                                           \
  }
  QROWR(0, y0) QROWR(1, y1) QROWR(2, y2) QROWR(3, y3)
#undef QROWR
}

// Build W = V^dagger (pass 0) or V^T (pass 1); packed half2 tables in SGPRs.
__device__ void compute_W(const float* __restrict__ wgt, int pass,
                          unsigned (&Wre2)[4][4], unsigned (&Wimn)[4][4],
                          unsigned (&Wri)[4][4]) {
  const float WMUL = 0.6324555320336759f;  // sqrt(0.4)
  float ca[6], sa[6];
  #pragma unroll
  for (int i = 0; i < 6; ++i) {
    float h = wgt[i] * (0.5f * WMUL);
    ca[i] = cosf(h);
    sa[i] = sinf(h);
  }
  float R01[4][4], R34[4][4];
  {
    float a0[2][2] = {{ca[0], -sa[0]}, {sa[0], ca[0]}};
    float b0[2][2] = {{ca[1], -sa[1]}, {sa[1], ca[1]}};
    float a1[2][2] = {{ca[3], -sa[3]}, {sa[3], ca[3]}};
    float b1[2][2] = {{ca[4], -sa[4]}, {sa[4], ca[4]}};
    #pragma unroll
    for (int i = 0; i < 4; ++i)
      #pragma unroll
      for (int j = 0; j < 4; ++j) {
        R01[i][j] = a0[i >> 1][j >> 1] * b0[i & 1][j & 1];
        R34[i][j] = a1[i >> 1][j >> 1] * b1[i & 1][j & 1];
      }
  }
  float M2re[4][4], M2im[4][4];
  #pragma unroll
  for (int k = 0; k < 4; ++k)
    #pragma unroll
    for (int j = 0; j < 4; ++j) {
      M2re[k][j] = ca[2] * R01[k][j];
      M2im[k][j] = -sa[2] * R01[3 - k][j];
    }
  float M3re[4][4], M3im[4][4];
  #pragma unroll
  for (int i = 0; i < 4; ++i)
    #pragma unroll
    for (int j = 0; j < 4; ++j) {
      float rr = 0.f, ii = 0.f;
      #pragma unroll
      for (int k = 0; k < 4; ++k) {
        rr += R34[i][k] * M2re[k][j];
        ii += R34[i][k] * M2im[k][j];
      }
      M3re[i][j] = rr;
      M3im[i][j] = ii;
    }
  #pragma unroll
  for (int k = 0; k < 4; ++k)
    #pragma unroll
    for (int j = 0; j < 4; ++j) {
      float vre = ca[5] * M3re[k][j] + sa[5] * M3im[3 - k][j];
      float vim = ca[5] * M3im[k][j] - sa[5] * M3re[3 - k][j];
      float wim = (pass == 0) ? -vim : vim;
      Wre2[j][k] = rflu(h2u(__floats2half2_rn(vre, vre)));
      Wimn[j][k] = rflu(h2u(__floats2half2_rn(-wim, wim)));
      Wri[j][k] = rflu(h2u(__floats2half2_rn(vre, wim)));
    }
}

// One pass over a 1024 x 8 column block; result written TRANSPOSED.
// 3 phases, 2 barriers. Row index r = d0*256 + d1*64 + d2*16 + d3*4 + d4.
// phase0: global load + digit d0 (stride 256) in registers + LDS stage
// S1:     digits d2,d1 (strides 16, 64)
// S2:     digits d4,d3 (strides 1, 4) + transposed writeout
// PASS 0: src = X (fp32, batch bg), dst = ws (complex fp16, chunk-local bl)
// PASS 1: src = ws (complex fp16, bl), dst = d_out fp32 real/imag planes (bg)
template <int PASS>
__global__ __launch_bounds__(512, 4) void qpass(const void* __restrict__ srcv,
                                                const float* __restrict__ weight,
                                                void* __restrict__ dstv,
                                                int batch0) {
  __shared__ __half2 tile[DIM * LSTRIDE];
  const int t = threadIdx.x;

  int B = blockIdx.x;
  int total = gridDim.x;
  int L;
  if ((total & 7) == 0) {
    int q = total >> 3;
    L = (B & 7) * q + (B >> 3);
  } else {
    L = B;
  }
  const int cg = L & 127;        // column group within batch (128 x 8 cols)
  const int bl = L >> 7;         // chunk-local batch (ws index)
  const int bg = batch0 + bl;    // global batch (x / out index)
  const int c0 = cg * CBLK;

  unsigned Wre2[4][4], Wimn[4][4], Wri[4][4];
  compute_W(weight, PASS, Wre2, Wimn, Wri);

  // ---- phase 0: load + digit d0 (stride 256) + stage ----
  {
    const int r0 = t >> 1;        // 0..255
    const int h = (t & 1) * 4;    // 0 or 4
    if (PASS == 0) {
      const float* s = (const float*)srcv + (size_t)bg * DIM * DIM +
                       (size_t)r0 * DIM + c0 + h;
      float4 la = *reinterpret_cast<const float4*>(s);
      float4 lb = *reinterpret_cast<const float4*>(s + (size_t)256 * DIM);
      float4 lc = *reinterpret_cast<const float4*>(s + (size_t)512 * DIM);
      float4 ld = *reinterpret_cast<const float4*>(s + (size_t)768 * DIM);
#define P0COL(j, CMP)                                                     \
      {                                                                   \
        __half2 y0, y1, y2, y3;                                           \
        cmv4r(h2dup(la.CMP), h2dup(lb.CMP), h2dup(lc.CMP), h2dup(ld.CMP), \
              y0, y1, y2, y3, Wri);                                       \
        tile[lidx(r0 + 0,   h + j)] = y0;                                 \
        tile[lidx(r0 + 256, h + j)] = y1;                                 \
        tile[lidx(r0 + 512, h + j)] = y2;                                 \
        tile[lidx(r0 + 768, h + j)] = y3;                                 \
      }
      P0COL(0, x) P0COL(1, y) P0COL(2, z) P0COL(3, w)
#undef P0COL
    } else {
      const __half2* s = (const __half2*)srcv + ((size_t)bl << 20) +
                         (size_t)r0 * DIM + c0 + h;
      H2x4 la = *reinterpret_cast<const H2x4*>(s);
      H2x4 lb = *reinterpret_cast<const H2x4*>(s + (size_t)256 * DIM);
      H2x4 lc = *reinterpret_cast<const H2x4*>(s + (size_t)512 * DIM);
      H2x4 ld = *reinterpret_cast<const H2x4*>(s + (size_t)768 * DIM);
#define P0COL(j)                                                          \
      {                                                                   \
        __half2 y0, y1, y2, y3;                                           \
        cmv4(la.h[j], lb.h[j], lc.h[j], ld.h[j],                          \
             y0, y1, y2, y3, Wre2, Wimn);                                 \
        tile[lidx(r0 + 0,   h + j)] = y0;                                 \
        tile[lidx(r0 + 256, h + j)] = y1;                                 \
        tile[lidx(r0 + 512, h + j)] = y2;                                 \
        tile[lidx(r0 + 768, h + j)] = y3;                                 \
      }
      P0COL(0) P0COL(1) P0COL(2) P0COL(3)
#undef P0COL
    }
  }
  __syncthreads();

  // ---- S1: digits d2,d1 (row strides 16, 64) ---- 1 item/thread
  {
    int c = t & 7, gg = t >> 3;              // gg in [0,64): (d0, d3, d4)
    int base = (gg >> 4) * 256 + (gg & 15);  // d0=(gg>>4), d3*4+d4=(gg&15)
    __half2 v[16];
    #pragma unroll
    for (int k1 = 0; k1 < 4; ++k1)
      #pragma unroll
      for (int k2 = 0; k2 < 4; ++k2)
        v[k1 * 4 + k2] = tile[lidx(base + k1 * 64 + k2 * 16, c)];
    #pragma unroll
    for (int k1 = 0; k1 < 4; ++k1) mv4p(&v[k1 * 4], 1, Wre2, Wimn);  // d2
    #pragma unroll
    for (int k2 = 0; k2 < 4; ++k2) mv4p(&v[k2], 4, Wre2, Wimn);      // d1
    #pragma unroll
    for (int k1 = 0; k1 < 4; ++k1)
      #pragma unroll
      for (int k2 = 0; k2 < 4; ++k2)
        tile[lidx(base + k1 * 64 + k2 * 16, c)] = v[k1 * 4 + k2];
  }
  __syncthreads();

  // ---- S2: digits d4,d3 (row strides 1, 4) + transposed writeout ----
  {
    int c = t & 7, q = t >> 3;  // rows 16q..16q+15, tile column c
    __half2 v[16];
    #pragma unroll
    for (int k = 0; k < 16; ++k) v[k] = tile[lidx(16 * q + k, c)];
    #pragma unroll
    for (int k3 = 0; k3 < 4; ++k3) mv4p(&v[4 * k3], 1, Wre2, Wimn);  // d4
    #pragma unroll
    for (int k4 = 0; k4 < 4; ++k4) mv4p(&v[k4], 4, Wre2, Wimn);      // d3
    if (PASS == 0) {
      // ws layout: complex-fp16 Tt[bl][k=c0+c][i=16q..16q+15] — 64 B/lane
      __half2* d = (__half2*)dstv + ((size_t)bl << 20) +
                   (size_t)(c0 + c) * DIM + 16 * q;
#define WOUT0(g4)                                                         \
      {                                                                   \
        H2x4 o;                                                           \
        o.h[0] = v[4 * g4 + 0];                                           \
        o.h[1] = v[4 * g4 + 1];                                           \
        o.h[2] = v[4 * g4 + 2];                                           \
        o.h[3] = v[4 * g4 + 3];                                           \
        *reinterpret_cast<H2x4*>(d + 4 * g4) = o;                         \
      }
      WOUT0(0) WOUT0(1) WOUT0(2) WOUT0(3)
#undef WOUT0
    } else {
      float* dr = (float*)dstv + ((size_t)bg << 20) +
                  (size_t)(c0 + c) * DIM + 16 * q;
      float* di = dr + ((size_t)1 << 23);
#define WOUT1(g4)                                                         \
      {                                                                   \
        float2 f0 = __half22float2(v[4 * g4 + 0]);                        \
        float2 f1 = __half22float2(v[4 * g4 + 1]);                        \
        float2 f2 = __half22float2(v[4 * g4 + 2]);                        \
        float2 f3 = __half22float2(v[4 * g4 + 3]);                        \
        vfloat4 re = {f0.x, f1.x, f2.x, f3.x};                            \
        vfloat4 im = {f0.y, f1.y, f2.y, f3.y};                            \
        __builtin_nontemporal_store(re,                                   \
            reinterpret_cast<vfloat4*>(dr + 4 * g4));                     \
        __builtin_nontemporal_store(im,                                   \
            reinterpret_cast<vfloat4*>(di + 4 * g4));                     \
      }
      WOUT1(0) WOUT1(1) WOUT1(2) WOUT1(3)
#undef WOUT1
    }
  }
}

extern "C" void kernel_launch(void* const* d_in, const int* in_sizes, int n_in,
                              void* d_out, int out_size, void* d_ws, size_t ws_size,
                              hipStream_t stream) {
  const float* x = (const float*)d_in[0];
  const float* w = (const float*)d_in[1];

  const size_t per_batch = (size_t)DIM * DIM * sizeof(__half2);  // 4 MB complex fp16
  int max_nb = (int)(ws_size / per_batch);
  if (max_nb > NB) max_nb = NB;
  if (max_nb < 1) max_nb = 1;  // assume ws >= 4 MB

  for (int b0 = 0; b0 < NB; b0 += max_nb) {
    int nb = NB - b0 < max_nb ? NB - b0 : max_nb;
    dim3 grid(128 * nb);
    qpass<0><<<grid, 512, 0, stream>>>(x, w, d_ws, b0);
    qpass<1><<<grid, 512, 0, stream>>>(d_ws, w, d_out, b0);
  }
}

// Round 10
// 53.413 us; speedup vs baseline: 2.6790x; 2.6790x over previous
//
#include <hip/hip_runtime.h>
#include <hip/hip_fp16.h>

#define DIM 1024
#define NB 8
#define CBLK 8
#define LSTRIDE 9  // half2 elements per row: 8 + 1 pad -> 36 B row stride

typedef float vfloat4 __attribute__((ext_vector_type(4)));  // native vec for nontemporal builtin

// LDS tile: 1024 rows x (8+1) half2 = 36864 B -> 4 blocks/CU.
__device__ __forceinline__ int lidx(int r, int c) {
  return r * LSTRIDE + c;
}

__device__ __forceinline__ unsigned rflu(unsigned x) {
  return (unsigned)__builtin_amdgcn_readfirstlane((int)x);
}
__device__ __forceinline__ unsigned h2u(__half2 h) {
  union { __half2 h; unsigned u; } c; c.h = h; return c.u;
}
__device__ __forceinline__ __half2 u2h(unsigned u) {
  union { unsigned u; __half2 h; } c; c.u = u; return c.h;
}
// swap halves: (a,b) -> (b,a)
__device__ __forceinline__ __half2 h2swap(__half2 x) {
  unsigned u = h2u(x);
  return u2h((u >> 16) | (u << 16));
}

struct __align__(16) H2x4 { __half2 h[4]; };

// Packed complex 4x4 matvec, in place along `stride`. half2 = (re, im).
// y = W x : Wre2*x + Wimn*swap(x), Wre2=(Wre,Wre), Wimn=(-Wim,+Wim)
__device__ __forceinline__ void mv4p(__half2* v, const int stride,
                                     const unsigned (&Wre2)[4][4],
                                     const unsigned (&Wimn)[4][4]) {
  __half2 x0 = v[0], x1 = v[stride], x2 = v[2 * stride], x3 = v[3 * stride];
  __half2 s0 = h2swap(x0), s1 = h2swap(x1), s2 = h2swap(x2), s3 = h2swap(x3);
  #pragma unroll
  for (int p = 0; p < 4; ++p) {
    __half2 a = u2h(Wre2[p][0]) * x0;
    a = __hfma2(u2h(Wimn[p][0]), s0, a);
    a = __hfma2(u2h(Wre2[p][2]), x2, a);
    a = __hfma2(u2h(Wimn[p][2]), s2, a);
    __half2 b = u2h(Wre2[p][1]) * x1;
    b = __hfma2(u2h(Wimn[p][1]), s1, b);
    b = __hfma2(u2h(Wre2[p][3]), x3, b);
    b = __hfma2(u2h(Wimn[p][3]), s3, b);
    v[p * stride] = a + b;
  }
}

// Real-input packed variant: x[k] = (re,re); Wri=(Wre,Wim);
// y[p] = sum_k (Wre*re, Wim*re) — one packed op per term.
__device__ __forceinline__ void mv4rp(const __half2* x, __half2* y,
                                      const unsigned (&Wri)[4][4]) {
  #pragma unroll
  for (int p = 0; p < 4; ++p) {
    __half2 a = u2h(Wri[p][0]) * x[0];
    a = __hfma2(u2h(Wri[p][2]), x[2], a);
    __half2 b = u2h(Wri[p][1]) * x[1];
    b = __hfma2(u2h(Wri[p][3]), x[3], b);
    y[p] = a + b;
  }
}

// Build W = V^dagger (pass 0) or V^T (pass 1); packed half2 tables in SGPRs.
__device__ void compute_W(const float* __restrict__ wgt, int pass,
                          unsigned (&Wre2)[4][4], unsigned (&Wimn)[4][4],
                          unsigned (&Wri)[4][4]) {
  const float WMUL = 0.6324555320336759f;  // sqrt(0.4)
  float ca[6], sa[6];
  #pragma unroll
  for (int i = 0; i < 6; ++i) {
    float h = wgt[i] * (0.5f * WMUL);
    ca[i] = cosf(h);
    sa[i] = sinf(h);
  }
  float R01[4][4], R34[4][4];
  {
    float a0[2][2] = {{ca[0], -sa[0]}, {sa[0], ca[0]}};
    float b0[2][2] = {{ca[1], -sa[1]}, {sa[1], ca[1]}};
    float a1[2][2] = {{ca[3], -sa[3]}, {sa[3], ca[3]}};
    float b1[2][2] = {{ca[4], -sa[4]}, {sa[4], ca[4]}};
    #pragma unroll
    for (int i = 0; i < 4; ++i)
      #pragma unroll
      for (int j = 0; j < 4; ++j) {
        R01[i][j] = a0[i >> 1][j >> 1] * b0[i & 1][j & 1];
        R34[i][j] = a1[i >> 1][j >> 1] * b1[i & 1][j & 1];
      }
  }
  float M2re[4][4], M2im[4][4];
  #pragma unroll
  for (int k = 0; k < 4; ++k)
    #pragma unroll
    for (int j = 0; j < 4; ++j) {
      M2re[k][j] = ca[2] * R01[k][j];
      M2im[k][j] = -sa[2] * R01[3 - k][j];
    }
  float M3re[4][4], M3im[4][4];
  #pragma unroll
  for (int i = 0; i < 4; ++i)
    #pragma unroll
    for (int j = 0; j < 4; ++j) {
      float rr = 0.f, ii = 0.f;
      #pragma unroll
      for (int k = 0; k < 4; ++k) {
        rr += R34[i][k] * M2re[k][j];
        ii += R34[i][k] * M2im[k][j];
      }
      M3re[i][j] = rr;
      M3im[i][j] = ii;
    }
  #pragma unroll
  for (int k = 0; k < 4; ++k)
    #pragma unroll
    for (int j = 0; j < 4; ++j) {
      float vre = ca[5] * M3re[k][j] + sa[5] * M3im[3 - k][j];
      float vim = ca[5] * M3im[k][j] - sa[5] * M3re[3 - k][j];
      // W[j][k] = V[k][j] (conj for pass 0)
      float wim = (pass == 0) ? -vim : vim;
      Wre2[j][k] = rflu(h2u(__floats2half2_rn(vre, vre)));
      Wimn[j][k] = rflu(h2u(__floats2half2_rn(-wim, wim)));
      Wri[j][k] = rflu(h2u(__floats2half2_rn(vre, wim)));
    }
}

// One pass over a 1024 x 8 column block; result written TRANSPOSED.
// R6-proven 4-phase structure (3 barriers). R8/R9 lesson: fusing digit-0 into
// the load phase (2-barrier variant) poisons codegen twice — compiler drops
// W tables out of SGPRs and spills stage arrays to scratch (VGPR=36, SGPR=48,
// WRITE_SIZE 161 MB, 2.5x slowdown). Do NOT restructure phase 0.
// PASS 0: src = X (fp32, batch bg), dst = ws (complex fp16, chunk-local bl)
// PASS 1: src = ws (complex fp16, bl), dst = d_out fp32 real/imag planes (bg)
// NOTE: min-waves/EU stays 4 — demanding 8 caps VGPRs at 64 and spills
// (R4: VGPR=32, WRITE_SIZE 137 MB, 2x slowdown).
template <int PASS>
__global__ __launch_bounds__(512, 4) void qpass(const void* __restrict__ srcv,
                                                const float* __restrict__ weight,
                                                void* __restrict__ dstv,
                                                int batch0) {
  __shared__ __half2 tile[DIM * LSTRIDE];
  const int t = threadIdx.x;

  int B = blockIdx.x;
  int total = gridDim.x;
  int L;
  if ((total & 7) == 0) {
    int q = total >> 3;
    L = (B & 7) * q + (B >> 3);
  } else {
    L = B;
  }
  const int cg = L & 127;        // column group within batch (128 x 8 cols)
  const int bl = L >> 7;         // chunk-local batch (ws index)
  const int bg = batch0 + bl;    // global batch (x / out index)
  const int c0 = cg * CBLK;

  unsigned Wre2[4][4], Wimn[4][4], Wri[4][4];
  compute_W(weight, PASS, Wre2, Wimn, Wri);

  // ---- load tile ----
  if (PASS == 0) {
    // real input staged as (re,re) so stage-1 digit uses 1-op/term mv4rp
    const float* s = (const float*)srcv + (size_t)bg * DIM * DIM + c0;
    #pragma unroll
    for (int it = 0; it < 4; ++it) {
      int u = it * 512 + t;            // 2048 float4 units
      int r = u >> 1, h = (u & 1) * 4;
      float4 v = *reinterpret_cast<const float4*>(s + (size_t)r * DIM + h);
      tile[lidx(r, h + 0)] = __half2half2(__float2half(v.x));
      tile[lidx(r, h + 1)] = __half2half2(__float2half(v.y));
      tile[lidx(r, h + 2)] = __half2half2(__float2half(v.z));
      tile[lidx(r, h + 3)] = __half2half2(__float2half(v.w));
    }
  } else {
    const __half2* s = (const __half2*)srcv + ((size_t)bl << 20) + c0;
    #pragma unroll
    for (int it = 0; it < 4; ++it) {
      int u = it * 512 + t;            // 2048 H2x4 units
      int r = u >> 1, h = (u & 1) * 4;
      H2x4 v = *reinterpret_cast<const H2x4*>(s + (size_t)r * DIM + h);
      tile[lidx(r, h + 0)] = v.h[0];
      tile[lidx(r, h + 1)] = v.h[1];
      tile[lidx(r, h + 2)] = v.h[2];
      tile[lidx(r, h + 3)] = v.h[3];
    }
  }
  __syncthreads();

  // ---- stage 1: digits 0,1 (row strides 256, 64) ---- 1 item/thread
  {
    int c = t & 7, g = t >> 3;  // g in [0,64): fixed digits 2,3,4
    __half2 v[16];
    if (PASS == 0) {
      #pragma unroll
      for (int k0 = 0; k0 < 4; ++k0) {
        __half2 xs[4];
        #pragma unroll
        for (int k1 = 0; k1 < 4; ++k1)
          xs[k1] = tile[lidx(g + k0 * 256 + k1 * 64, c)];
        mv4rp(xs, &v[k0 * 4], Wri);                                  // digit 1
      }
    } else {
      #pragma unroll
      for (int k0 = 0; k0 < 4; ++k0)
        #pragma unroll
        for (int k1 = 0; k1 < 4; ++k1)
          v[k0 * 4 + k1] = tile[lidx(g + k0 * 256 + k1 * 64, c)];
      #pragma unroll
      for (int k0 = 0; k0 < 4; ++k0) mv4p(&v[k0 * 4], 1, Wre2, Wimn);  // digit 1
    }
    #pragma unroll
    for (int k1 = 0; k1 < 4; ++k1) mv4p(&v[k1], 4, Wre2, Wimn);        // digit 0
    #pragma unroll
    for (int k0 = 0; k0 < 4; ++k0)
      #pragma unroll
      for (int k1 = 0; k1 < 4; ++k1)
        tile[lidx(g + k0 * 256 + k1 * 64, c)] = v[k0 * 4 + k1];
  }
  __syncthreads();

  // ---- stage 2: digits 2,3 (row strides 16, 4) ---- 1 item/thread
  {
    int c = t & 7, g = t >> 3;
    int base = (g >> 2) * 64 + (g & 3);  // fixed digits 0,1 (g>>2) and 4 (g&3)
    __half2 v[16];
    #pragma unroll
    for (int k2 = 0; k2 < 4; ++k2)
      #pragma unroll
      for (int k3 = 0; k3 < 4; ++k3)
        v[k2 * 4 + k3] = tile[lidx(base + k2 * 16 + k3 * 4, c)];
    #pragma unroll
    for (int k2 = 0; k2 < 4; ++k2) mv4p(&v[k2 * 4], 1, Wre2, Wimn);  // digit 3
    #pragma unroll
    for (int k3 = 0; k3 < 4; ++k3) mv4p(&v[k3], 4, Wre2, Wimn);      // digit 2
    #pragma unroll
    for (int k2 = 0; k2 < 4; ++k2)
      #pragma unroll
      for (int k3 = 0; k3 < 4; ++k3)
        tile[lidx(base + k2 * 16 + k3 * 4, c)] = v[k2 * 4 + k3];
  }
  __syncthreads();

  // ---- stage 3: digit 4 (stride 1) + transposed writeout ----
  #pragma unroll
  for (int it = 0; it < 4; ++it) {
    int c = t & 7;
    int g = (t >> 3) + 64 * it;  // row group: rows 4g..4g+3
    __half2 v[4];
    #pragma unroll
    for (int k = 0; k < 4; ++k) v[k] = tile[lidx(4 * g + k, c)];
    mv4p(v, 1, Wre2, Wimn);
    if (PASS == 0) {
      // ws layout: complex-fp16 Tt[bl][k=c0+c][i=4g..4g+3]
      // (ws IS re-read by pass 1 -> keep cached, no nontemporal)
      __half2* d = (__half2*)dstv + ((size_t)bl << 20) + (size_t)(c0 + c) * DIM + 4 * g;
      H2x4 o;
      o.h[0] = v[0]; o.h[1] = v[1]; o.h[2] = v[2]; o.h[3] = v[3];
      *reinterpret_cast<H2x4*>(d) = o;
    } else {
      // out[0][bg][i=c0+c][j=4g..4g+3] (real), out[1][...] (imag)
      // final output is never re-read -> nontemporal, keep L2 for ws
      float2 f0 = __half22float2(v[0]), f1 = __half22float2(v[1]);
      float2 f2 = __half22float2(v[2]), f3 = __half22float2(v[3]);
      float* dr = (float*)dstv + ((size_t)bg << 20) + (size_t)(c0 + c) * DIM + 4 * g;
      float* di = dr + ((size_t)1 << 23);
      vfloat4 re = {f0.x, f1.x, f2.x, f3.x};
      vfloat4 im = {f0.y, f1.y, f2.y, f3.y};
      __builtin_nontemporal_store(re, reinterpret_cast<vfloat4*>(dr));
      __builtin_nontemporal_store(im, reinterpret_cast<vfloat4*>(di));
    }
  }
}

extern "C" void kernel_launch(void* const* d_in, const int* in_sizes, int n_in,
                              void* d_out, int out_size, void* d_ws, size_t ws_size,
                              hipStream_t stream) {
  const float* x = (const float*)d_in[0];
  const float* w = (const float*)d_in[1];

  const size_t per_batch = (size_t)DIM * DIM * sizeof(__half2);  // 4 MB complex fp16
  int max_nb = (int)(ws_size / per_batch);
  if (max_nb > NB) max_nb = NB;
  if (max_nb < 1) max_nb = 1;  // assume ws >= 4 MB

  for (int b0 = 0; b0 < NB; b0 += max_nb) {
    int nb = NB - b0 < max_nb ? NB - b0 : max_nb;
    dim3 grid(128 * nb);
    qpass<0><<<grid, 512, 0, stream>>>(x, w, d_ws, b0);
    qpass<1><<<grid, 512, 0, stream>>>(d_ws, w, d_out, b0);
  }
}